// Round 1
// baseline (140.838 us; speedup 1.0000x reference)
//
#include <hip/hip_runtime.h>
#include <hip/hip_bf16.h>

typedef __attribute__((ext_vector_type(8))) short bf16x8;
typedef __attribute__((ext_vector_type(4))) float f32x4;

#define MFMA16(a,b,c) __builtin_amdgcn_mfma_f32_16x16x32_bf16((a),(b),(c),0,0,0)

__device__ __forceinline__ unsigned short f2bf(float f) {
    unsigned int u = __builtin_bit_cast(unsigned int, f);
    u += 0x7fffu + ((u >> 16) & 1u);
    return (unsigned short)(u >> 16);
}

// Problem constants (from setup_inputs: B=2, T=2048, D=2048, d=1024, kv=64)
#define BT     4096   // B*T rows
#define DFULL  2048
#define DACT   1024
#define NHEAD  8
#define DKV    64
#define NSEL   512    // NHEAD*DKV
#define TSEQ   2048
#define PADR   72     // padded LDS row stride in shorts (144B)

// ---------------------------------------------------------------------------
// Kernel 1: convert xs -> bf16, selected W rows/cols -> bf16, zero pad cols
// ---------------------------------------------------------------------------
__global__ __launch_bounds__(256) void prep_kernel(
    const float* __restrict__ x,  const float* __restrict__ Wq,
    const float* __restrict__ Wk, const float* __restrict__ Wv,
    const float* __restrict__ Wo,
    unsigned short* __restrict__ xb,  unsigned short* __restrict__ Wqb,
    unsigned short* __restrict__ Wkb, unsigned short* __restrict__ Wvb,
    unsigned short* __restrict__ Wob, float* __restrict__ out)
{
    const int NA = (BT * DACT) / 8;        // 524288
    const int NB = (NSEL * DACT) / 8;      // 65536 (per W matrix)
    const int NC = (DACT * NSEL) / 8;      // 65536
    const int ND = (BT * DACT) / 8;        // 524288 zero units
    const int TOT = NA + 3 * NB + NC + ND;
    for (int u = blockIdx.x * blockDim.x + threadIdx.x; u < TOT;
         u += gridDim.x * blockDim.x) {
        if (u < NA) {
            int e = u * 8; int row = e >> 10, col = e & 1023;
            const float* s = x + (size_t)row * DFULL + col;
            f32x4 v0 = *(const f32x4*)s, v1 = *(const f32x4*)(s + 4);
            bf16x8 o;
            #pragma unroll
            for (int j = 0; j < 4; ++j) { o[j] = (short)f2bf(v0[j]); o[4+j] = (short)f2bf(v1[j]); }
            *(bf16x8*)(xb + e) = o;
        } else if (u < NA + 3 * NB) {
            int t = u - NA; int mat = t / NB; int q = t % NB;
            int e = q * 8; int n = e >> 10, c = e & 1023;
            const float* W = (mat == 0) ? Wq : (mat == 1) ? Wk : Wv;
            unsigned short* Wb = (mat == 0) ? Wqb : (mat == 1) ? Wkb : Wvb;
            int wrow = (n >> 6) * 128 + (n & 63);
            const float* s = W + (size_t)wrow * DFULL + c;
            f32x4 v0 = *(const f32x4*)s, v1 = *(const f32x4*)(s + 4);
            bf16x8 o;
            #pragma unroll
            for (int j = 0; j < 4; ++j) { o[j] = (short)f2bf(v0[j]); o[4+j] = (short)f2bf(v1[j]); }
            *(bf16x8*)(Wb + e) = o;
        } else if (u < NA + 3 * NB + NC) {
            int q = u - NA - 3 * NB;
            int e = q * 8; int r = e >> 9, cs = e & 511;
            int col = (cs >> 6) * 128 + (cs & 63);       // 8 consecutive stay in-head
            const float* s = Wo + (size_t)r * DFULL + col;
            f32x4 v0 = *(const f32x4*)s, v1 = *(const f32x4*)(s + 4);
            bf16x8 o;
            #pragma unroll
            for (int j = 0; j < 4; ++j) { o[j] = (short)f2bf(v0[j]); o[4+j] = (short)f2bf(v1[j]); }
            *(bf16x8*)(Wob + e) = o;
        } else {
            int q = u - (NA + 3 * NB + NC);
            int e = q * 8; int row = e >> 10, col = e & 1023;
            float* dp = out + (size_t)row * DFULL + DACT + col;
            f32x4 z = {0.f, 0.f, 0.f, 0.f};
            *(f32x4*)dp = z; *(f32x4*)(dp + 4) = z;
        }
    }
}

// ---------------------------------------------------------------------------
// Kernel 2: QKV projection.  C[m, (h,j)] = sum_c xb[m,c] * Wb[h*64+j, c]
// grid = (32, 24): y = mat*8 + h.  Block 256 = 4 waves, each wave 32x64.
// Q -> [bh][t][64]*0.125 bf16 ; K -> [bh][t][64] ; V -> transposed [bh][64][t]
// ---------------------------------------------------------------------------
__global__ __launch_bounds__(256) void qkv_gemm(
    const unsigned short* __restrict__ xb,
    const unsigned short* __restrict__ Wqb,
    const unsigned short* __restrict__ Wkb,
    const unsigned short* __restrict__ Wvb,
    unsigned short* __restrict__ Qb, unsigned short* __restrict__ Kb,
    unsigned short* __restrict__ Vtb)
{
    __shared__ unsigned short As[128 * PADR];
    __shared__ unsigned short Bs[64 * PADR];
    const int m0 = blockIdx.x * 128;
    const int gy = blockIdx.y;
    const int mat = gy >> 3, h = gy & 7;
    const unsigned short* Wb = (mat == 0) ? Wqb : (mat == 1) ? Wkb : Wvb;
    const int tid = threadIdx.x, w = tid >> 6, l = tid & 63;
    const int lr = l & 15, g = l >> 4, lk = g * 8;

    f32x4 acc[2][4] = {};
    for (int k0 = 0; k0 < DACT; k0 += 64) {
        __syncthreads();
        #pragma unroll
        for (int i = 0; i < 4; ++i) {
            int u = tid + i * 256; int row = u >> 3, un = u & 7;
            *(bf16x8*)&As[row * PADR + un * 8] =
                *(const bf16x8*)&xb[(size_t)(m0 + row) * DACT + k0 + un * 8];
        }
        #pragma unroll
        for (int i = 0; i < 2; ++i) {
            int u = tid + i * 256; int row = u >> 3, un = u & 7;
            *(bf16x8*)&Bs[row * PADR + un * 8] =
                *(const bf16x8*)&Wb[(size_t)(h * 64 + row) * DACT + k0 + un * 8];
        }
        __syncthreads();
        #pragma unroll
        for (int kk = 0; kk < 64; kk += 32) {
            bf16x8 a[2], b[4];
            #pragma unroll
            for (int m = 0; m < 2; ++m)
                a[m] = *(const bf16x8*)&As[(w * 32 + m * 16 + lr) * PADR + kk + lk];
            #pragma unroll
            for (int n = 0; n < 4; ++n)
                b[n] = *(const bf16x8*)&Bs[(n * 16 + lr) * PADR + kk + lk];
            #pragma unroll
            for (int m = 0; m < 2; ++m)
                #pragma unroll
                for (int n = 0; n < 4; ++n)
                    acc[m][n] = MFMA16(a[m], b[n], acc[m][n]);
        }
    }
    // epilogue
    #pragma unroll
    for (int m = 0; m < 2; ++m) {
        #pragma unroll
        for (int n = 0; n < 4; ++n) {
            #pragma unroll
            for (int i = 0; i < 4; ++i) {
                int row = m0 + w * 32 + m * 16 + g * 4 + i;   // global m
                int bb = row >> 11, t = row & 2047;
                int bh = bb * 8 + h;
                int j = n * 16 + lr;
                float v = acc[m][n][i];
                if (mat == 0)
                    Qb[((size_t)bh * TSEQ + t) * DKV + j] = f2bf(v * 0.125f);
                else if (mat == 1)
                    Kb[((size_t)bh * TSEQ + t) * DKV + j] = f2bf(v);
                else
                    Vtb[((size_t)bh * DKV + j) * TSEQ + t] = f2bf(v);
            }
        }
    }
}

// ---------------------------------------------------------------------------
// Kernel 3: causal flash attention.  grid = (32 qtiles, 16 bh), block 256.
// Each wave owns 16 q-rows; K/V tiles (64 wide) staged in LDS.
// att out -> [m=(b,t)][cs=(h,j)] bf16  (rows of the final GEMM)
// ---------------------------------------------------------------------------
__global__ __launch_bounds__(256) void attn_kernel(
    const unsigned short* __restrict__ Qb,
    const unsigned short* __restrict__ Kb,
    const unsigned short* __restrict__ Vtb,
    unsigned short* __restrict__ att)
{
    __shared__ unsigned short Ks[64 * PADR];
    __shared__ unsigned short Vs[64 * PADR];
    __shared__ unsigned short Ps[64 * PADR];
    const int p = gridDim.x - 1 - blockIdx.x;   // heavy blocks first
    const int bh = blockIdx.y;
    const int qbase = p * 64;
    const int tid = threadIdx.x, w = tid >> 6, l = tid & 63;
    const int lr = l & 15, g = l >> 4, lk = g * 8;

    // Q fragments (rows qbase + w*16 + lr, k = lk..lk+7 and 32+lk..)
    bf16x8 qf[2];
    {
        size_t qrow = (size_t)bh * TSEQ + qbase + w * 16 + lr;
        qf[0] = *(const bf16x8*)&Qb[qrow * DKV + 0  + lk];
        qf[1] = *(const bf16x8*)&Qb[qrow * DKV + 32 + lk];
    }
    f32x4 acc[4] = {};
    float mi[4], li[4];
    #pragma unroll
    for (int i = 0; i < 4; ++i) { mi[i] = -3e38f; li[i] = 0.f; }

    for (int jt = 0; jt <= p; ++jt) {
        __syncthreads();
        #pragma unroll
        for (int i = 0; i < 2; ++i) {
            int u = tid + i * 256; int row = u >> 3, un = u & 7;
            *(bf16x8*)&Ks[row * PADR + un * 8] =
                *(const bf16x8*)&Kb[((size_t)bh * TSEQ + jt * 64 + row) * DKV + un * 8];
            *(bf16x8*)&Vs[row * PADR + un * 8] =
                *(const bf16x8*)&Vtb[((size_t)bh * DKV + row) * TSEQ + jt * 64 + un * 8];
        }
        __syncthreads();

        // S = Q K^T   (4 chunks of 16 kv cols)
        f32x4 s[4];
        #pragma unroll
        for (int c = 0; c < 4; ++c) {
            bf16x8 b0 = *(const bf16x8*)&Ks[(c * 16 + lr) * PADR + 0  + lk];
            bf16x8 b1 = *(const bf16x8*)&Ks[(c * 16 + lr) * PADR + 32 + lk];
            f32x4 z = {};
            z = MFMA16(qf[0], b0, z);
            z = MFMA16(qf[1], b1, z);
            s[c] = z;
        }
        // causal mask
        int qr0 = qbase + w * 16 + g * 4;
        #pragma unroll
        for (int c = 0; c < 4; ++c) {
            int kcol = jt * 64 + c * 16 + lr;
            #pragma unroll
            for (int i = 0; i < 4; ++i)
                if (kcol > qr0 + i) s[c][i] = -1e30f;
        }
        // online softmax (row stats live on all 16 lanes of each group)
        float tm[4];
        #pragma unroll
        for (int i = 0; i < 4; ++i)
            tm[i] = fmaxf(fmaxf(s[0][i], s[1][i]), fmaxf(s[2][i], s[3][i]));
        #pragma unroll
        for (int off = 1; off < 16; off <<= 1)
            #pragma unroll
            for (int i = 0; i < 4; ++i)
                tm[i] = fmaxf(tm[i], __shfl_xor(tm[i], off));
        float al[4];
        #pragma unroll
        for (int i = 0; i < 4; ++i) {
            float mn = fmaxf(mi[i], tm[i]);
            al[i] = __expf(mi[i] - mn);
            mi[i] = mn;
        }
        f32x4 pv[4];
        float rs[4] = {0.f, 0.f, 0.f, 0.f};
        #pragma unroll
        for (int c = 0; c < 4; ++c)
            #pragma unroll
            for (int i = 0; i < 4; ++i) {
                float e = __expf(s[c][i] - mi[i]);
                pv[c][i] = e; rs[i] += e;
            }
        #pragma unroll
        for (int off = 1; off < 16; off <<= 1)
            #pragma unroll
            for (int i = 0; i < 4; ++i)
                rs[i] += __shfl_xor(rs[i], off);
        #pragma unroll
        for (int i = 0; i < 4; ++i) li[i] = li[i] * al[i] + rs[i];
        #pragma unroll
        for (int n = 0; n < 4; ++n)
            #pragma unroll
            for (int i = 0; i < 4; ++i)
                acc[n][i] *= al[i];
        // P: D-layout -> A-layout via wave-private LDS
        #pragma unroll
        for (int c = 0; c < 4; ++c)
            #pragma unroll
            for (int i = 0; i < 4; ++i)
                Ps[(w * 16 + g * 4 + i) * PADR + c * 16 + lr] = f2bf(pv[c][i]);
        bf16x8 pa0 = *(const bf16x8*)&Ps[(w * 16 + lr) * PADR + 0  + lk];
        bf16x8 pa1 = *(const bf16x8*)&Ps[(w * 16 + lr) * PADR + 32 + lk];
        // out += P V   (Vs[j][k] is V^T tile)
        #pragma unroll
        for (int n = 0; n < 4; ++n) {
            bf16x8 v0 = *(const bf16x8*)&Vs[(n * 16 + lr) * PADR + 0  + lk];
            bf16x8 v1 = *(const bf16x8*)&Vs[(n * 16 + lr) * PADR + 32 + lk];
            acc[n] = MFMA16(pa0, v0, acc[n]);
            acc[n] = MFMA16(pa1, v1, acc[n]);
        }
    }
    // epilogue
    int bb = bh >> 3, h = bh & 7;
    #pragma unroll
    for (int n = 0; n < 4; ++n)
        #pragma unroll
        for (int i = 0; i < 4; ++i) {
            int t = qbase + w * 16 + g * 4 + i;
            float o = acc[n][i] / li[i];
            att[((size_t)bb * TSEQ + t) * NSEL + h * 64 + n * 16 + lr] = f2bf(o);
        }
}

// ---------------------------------------------------------------------------
// Kernel 4: output projection.  out[m,r] = sum_cs att[m,cs] * Wob[r,cs]
// grid = (32, 8), block 256 = 4 waves (2x2), 128x128 tile, K=512.
// ---------------------------------------------------------------------------
__global__ __launch_bounds__(256) void oproj_gemm(
    const unsigned short* __restrict__ att,
    const unsigned short* __restrict__ Wob,
    float* __restrict__ out)
{
    __shared__ unsigned short As[128 * PADR];
    __shared__ unsigned short Bs[128 * PADR];
    const int m0 = blockIdx.x * 128, n0 = blockIdx.y * 128;
    const int tid = threadIdx.x, w = tid >> 6, l = tid & 63;
    const int lr = l & 15, g = l >> 4, lk = g * 8;
    const int wr = w >> 1, wc = w & 1;

    f32x4 acc[4][4] = {};
    for (int k0 = 0; k0 < NSEL; k0 += 64) {
        __syncthreads();
        #pragma unroll
        for (int i = 0; i < 4; ++i) {
            int u = tid + i * 256; int row = u >> 3, un = u & 7;
            *(bf16x8*)&As[row * PADR + un * 8] =
                *(const bf16x8*)&att[(size_t)(m0 + row) * NSEL + k0 + un * 8];
            *(bf16x8*)&Bs[row * PADR + un * 8] =
                *(const bf16x8*)&Wob[(size_t)(n0 + row) * NSEL + k0 + un * 8];
        }
        __syncthreads();
        #pragma unroll
        for (int kk = 0; kk < 64; kk += 32) {
            bf16x8 a[4], b[4];
            #pragma unroll
            for (int m = 0; m < 4; ++m)
                a[m] = *(const bf16x8*)&As[(wr * 64 + m * 16 + lr) * PADR + kk + lk];
            #pragma unroll
            for (int n = 0; n < 4; ++n)
                b[n] = *(const bf16x8*)&Bs[(wc * 64 + n * 16 + lr) * PADR + kk + lk];
            #pragma unroll
            for (int m = 0; m < 4; ++m)
                #pragma unroll
                for (int n = 0; n < 4; ++n)
                    acc[m][n] = MFMA16(a[m], b[n], acc[m][n]);
        }
    }
    #pragma unroll
    for (int m = 0; m < 4; ++m)
        #pragma unroll
        for (int n = 0; n < 4; ++n)
            #pragma unroll
            for (int i = 0; i < 4; ++i) {
                int row = m0 + wr * 64 + m * 16 + g * 4 + i;
                int col = n0 + wc * 64 + n * 16 + lr;
                out[(size_t)row * DFULL + col] = acc[m][n][i];
            }
}

// ---------------------------------------------------------------------------
extern "C" void kernel_launch(void* const* d_in, const int* in_sizes, int n_in,
                              void* d_out, int out_size, void* d_ws, size_t ws_size,
                              hipStream_t stream) {
    const float* x  = (const float*)d_in[0];
    const float* Wq = (const float*)d_in[1];
    const float* Wk = (const float*)d_in[2];
    const float* Wv = (const float*)d_in[3];
    const float* Wo = (const float*)d_in[4];
    float* out = (float*)d_out;

    char* ws = (char*)d_ws;
    unsigned short* xb  = (unsigned short*)(ws);                    //  8 MB
    unsigned short* Wqb = (unsigned short*)(ws + 8388608);          //  1 MB
    unsigned short* Wkb = (unsigned short*)(ws + 9437184);
    unsigned short* Wvb = (unsigned short*)(ws + 10485760);
    unsigned short* Wob = (unsigned short*)(ws + 11534336);         //  1 MB
    unsigned short* Qb  = (unsigned short*)(ws + 12582912);         //  4 MB
    unsigned short* Kb  = (unsigned short*)(ws + 16777216);
    unsigned short* Vtb = (unsigned short*)(ws + 20971520);
    unsigned short* att = (unsigned short*)(ws + 25165824);         //  4 MB

    prep_kernel<<<2048, 256, 0, stream>>>(x, Wq, Wk, Wv, Wo,
                                          xb, Wqb, Wkb, Wvb, Wob, out);
    qkv_gemm<<<dim3(32, 24), 256, 0, stream>>>(xb, Wqb, Wkb, Wvb, Qb, Kb, Vtb);
    attn_kernel<<<dim3(32, 16), 256, 0, stream>>>(Qb, Kb, Vtb, att);
    oproj_gemm<<<dim3(32, 8), 256, 0, stream>>>(att, Wob, out);
}